// Round 5
// baseline (368.359 us; speedup 1.0000x reference)
//
#include <hip/hip_runtime.h>
#include <hip/hip_bf16.h>

typedef __attribute__((ext_vector_type(8))) __bf16 bf16x8;
typedef __attribute__((ext_vector_type(4))) float floatx4;
typedef __attribute__((ext_vector_type(4))) unsigned short us4;
typedef __attribute__((ext_vector_type(8))) unsigned short us8;
typedef __attribute__((ext_vector_type(4))) short s16x4;

#define MFMA16(A, B, C) __builtin_amdgcn_mfma_f32_16x16x32_bf16((A), (B), (C), 0, 0, 0)
// K=16 bf16 MFMA (gfx90a-era _1k, still present on gfx950): A,B are 4 x i16 bf16 bits
#define MFMA1K(A, B, C) __builtin_amdgcn_mfma_f32_16x16x16bf16_1k((A), (B), (C), 0, 0, 0)

static __device__ __forceinline__ unsigned short f2bfbits(float f) {
    __hip_bfloat16 h = __float2bfloat16(f);
    union { __hip_bfloat16 h; unsigned short u; } cv;
    cv.h = h;
    return cv.u;
}
static __device__ __forceinline__ bf16x8 load_bf8(const __hip_bfloat16* p) {
    return *reinterpret_cast<const bf16x8*>(p);
}
// 8 fp32 -> bf16x8 fragment (RN rounding)
static __device__ __forceinline__ bf16x8 cvt8(floatx4 a, floatx4 b) {
    us8 u;
#pragma unroll
    for (int i = 0; i < 4; i++) { u[i] = f2bfbits(a[i]); u[4 + i] = f2bfbits(b[i]); }
    return __builtin_bit_cast(bf16x8, u);
}

// ---------------------------------------------------------------------------
// K0: wT[p][d][c] = dw_p[c] * pw_p[c][d]   (bf16, transposed for B-frag loads)
// ---------------------------------------------------------------------------
__global__ __launch_bounds__(256) void prep_w(
    const float* __restrict__ dwq, const float* __restrict__ pwq,
    const float* __restrict__ dwk, const float* __restrict__ pwk,
    const float* __restrict__ dwv, const float* __restrict__ pwv,
    __hip_bfloat16* __restrict__ wT)
{
    int idx = blockIdx.x * 256 + threadIdx.x;   // < 49152
    int p = idx >> 14;
    int r = idx & 16383;
    int d = r >> 8, c = r & 255;
    const float* dw = (p == 0) ? dwq : ((p == 1) ? dwk : dwv);
    const float* pw = (p == 0) ? pwq : ((p == 1) ? pwk : pwv);
    wT[idx] = __float2bfloat16(dw[c] * pw[c * 64 + d]);
}

// ---------------------------------------------------------------------------
// K1: fused QKV projection. One wave per (16-row strip, proj).
//   x fp32 -> bf16 frags; q,k -> [row][64] bf16 ; v -> transposed [n][c][i]
// ---------------------------------------------------------------------------
__global__ __launch_bounds__(256) void proj_qkv(
    const float* __restrict__ x,
    const __hip_bfloat16* __restrict__ wT,
    const float* __restrict__ bqp, const float* __restrict__ bkp,
    const float* __restrict__ bvp,
    __hip_bfloat16* __restrict__ qb, __hip_bfloat16* __restrict__ kb,
    __hip_bfloat16* __restrict__ vt)
{
    int wid = blockIdx.x * 4 + (threadIdx.x >> 6);  // 0..3071
    int proj = wid >> 10;                            // 0=q 1=k 2=v
    int strip = (wid & 1023) << 4;                   // row base (global, 0..16368)
    int lane = threadIdx.x & 63;
    int l15 = lane & 15, quad = lane >> 4;

    const __hip_bfloat16* w = wT + proj * 16384;
    floatx4 acc[4];
#pragma unroll
    for (int t = 0; t < 4; t++) acc[t] = (floatx4){0.f, 0.f, 0.f, 0.f};

    const float* xrow = x + (strip + l15) * 256 + quad * 8;
#pragma unroll
    for (int ks = 0; ks < 8; ks++) {
        floatx4 xa = *reinterpret_cast<const floatx4*>(xrow + ks * 32);
        floatx4 xb = *reinterpret_cast<const floatx4*>(xrow + ks * 32 + 4);
        bf16x8 a = cvt8(xa, xb);
#pragma unroll
        for (int t = 0; t < 4; t++) {
            bf16x8 b = load_bf8(w + (t * 16 + l15) * 256 + ks * 32 + quad * 8);
            acc[t] = MFMA16(a, b, acc[t]);
        }
    }
    const float* bias = (proj == 0) ? bqp : ((proj == 1) ? bkp : bvp);
    if (proj < 2) {
        __hip_bfloat16* dst = (proj == 0) ? qb : kb;
#pragma unroll
        for (int t = 0; t < 4; t++) {
            int d = t * 16 + l15;
            float bsv = bias[d];
#pragma unroll
            for (int r = 0; r < 4; r++) {
                int m = strip + quad * 4 + r;
                dst[m * 64 + d] = __float2bfloat16(acc[t][r] + bsv);
            }
        }
    } else {
        int n = strip >> 12;
        int i0 = (strip & 4095) + quad * 4;
#pragma unroll
        for (int t = 0; t < 4; t++) {
            int d = t * 16 + l15;
            float bsv = bias[d];
            us4 pk;
#pragma unroll
            for (int r = 0; r < 4; r++) pk[r] = f2bfbits(acc[t][r] + bsv);
            *reinterpret_cast<us4*>(vt + (n * 64 + d) * 4096 + i0) = pk;
        }
    }
}

// ---------------------------------------------------------------------------
// K2: rl[i] = 1 / sum_j exp(k_i . q_j).  Block = 16-i strip, 8 waves split j
// (512 j each, 2 j-tiles per iter for ILP). 1024 blocks x 512 thr = 100% cap.
// ---------------------------------------------------------------------------
__global__ __launch_bounds__(512) void pass1_rl(
    const __hip_bfloat16* __restrict__ qb, const __hip_bfloat16* __restrict__ kb,
    float* __restrict__ rl)
{
    int n = blockIdx.x >> 8;
    int ibase = n * 4096 + ((blockIdx.x & 255) << 4);
    int widx = threadIdx.x >> 6;          // 0..7
    int lane = threadIdx.x & 63;
    int l15 = lane & 15, quad = lane >> 4;

    const __hip_bfloat16* kp = kb + (ibase + l15) * 64 + quad * 8;
    bf16x8 a0 = load_bf8(kp);
    bf16x8 a1 = load_bf8(kp + 32);

    float ls0 = 0.f, ls1 = 0.f, ls2 = 0.f, ls3 = 0.f;
    const __hip_bfloat16* qbase = qb + n * 4096 * 64;
    for (int jt = widx * 32; jt < widx * 32 + 32; jt += 2) {
        const __hip_bfloat16* qp0 = qbase + (jt * 16 + l15) * 64 + quad * 8;
        bf16x8 b0 = load_bf8(qp0);
        bf16x8 b1 = load_bf8(qp0 + 32);
        bf16x8 b2 = load_bf8(qp0 + 16 * 64);
        bf16x8 b3 = load_bf8(qp0 + 16 * 64 + 32);
        floatx4 s0 = (floatx4){0.f, 0.f, 0.f, 0.f};
        floatx4 s1 = (floatx4){0.f, 0.f, 0.f, 0.f};
        s0 = MFMA16(a0, b0, s0);
        s0 = MFMA16(a1, b1, s0);
        s1 = MFMA16(a0, b2, s1);
        s1 = MFMA16(a1, b3, s1);
        ls0 += __expf(s0[0]) + __expf(s1[0]);
        ls1 += __expf(s0[1]) + __expf(s1[1]);
        ls2 += __expf(s0[2]) + __expf(s1[2]);
        ls3 += __expf(s0[3]) + __expf(s1[3]);
    }
    // sum across the 16 j-columns held by the l15 group (xor masks stay in-quad)
#pragma unroll
    for (int m = 1; m < 16; m <<= 1) {
        ls0 += __shfl_xor(ls0, m, 64);
        ls1 += __shfl_xor(ls1, m, 64);
        ls2 += __shfl_xor(ls2, m, 64);
        ls3 += __shfl_xor(ls3, m, 64);
    }
    __shared__ float red[8][16];
    if (l15 == 0) {
        red[widx][quad * 4 + 0] = ls0;
        red[widx][quad * 4 + 1] = ls1;
        red[widx][quad * 4 + 2] = ls2;
        red[widx][quad * 4 + 3] = ls3;
    }
    __syncthreads();
    int tid = threadIdx.x;
    if (tid < 16) {
        float tot = 0.f;
#pragma unroll
        for (int w = 0; w < 8; w++) tot += red[w][tid];
        rl[ibase + tid] = 1.0f / tot;
    }
}

// ---------------------------------------------------------------------------
// K3: attT[n][c][j] = sum_i P[i,j] * v[i,c],  P = exp(s_ij) * rl_i.
// Block = 16-j strip, 8 waves split i (512 each). NO LDS transpose: the C/D
// layout of the 16x16 QK^T output (col=l15, row=quad*4+reg) IS the A-operand
// layout of the K=16 MFMA (m=l15, k=quad*4+j) -> pack exp(s)*rl in-register
// and feed v_mfma_f32_16x16x16_bf16 directly. Zero barriers in the K-loop.
// ---------------------------------------------------------------------------
__global__ __launch_bounds__(512) void pass2_att(
    const __hip_bfloat16* __restrict__ qb, const __hip_bfloat16* __restrict__ kb,
    const __hip_bfloat16* __restrict__ vt, const float* __restrict__ rl,
    float* __restrict__ attT)
{
    int n = blockIdx.x >> 8;
    int jbase = (blockIdx.x & 255) << 4;  // local j
    int widx = threadIdx.x >> 6;          // 0..7
    int lane = threadIdx.x & 63;
    int l15 = lane & 15, quad = lane >> 4;
    int rowbase = n * 4096;

    const __hip_bfloat16* qp = qb + (rowbase + jbase + l15) * 64 + quad * 8;
    bf16x8 bq0 = load_bf8(qp);
    bf16x8 bq1 = load_bf8(qp + 32);

    floatx4 acc[4];
#pragma unroll
    for (int t = 0; t < 4; t++) acc[t] = (floatx4){0.f, 0.f, 0.f, 0.f};

    const __hip_bfloat16* vbase = vt + (n * 64 + l15) * 4096;

    for (int i0 = widx * 512; i0 < widx * 512 + 512; i0 += 32) {
        const __hip_bfloat16* kp = kb + (rowbase + i0 + l15) * 64 + quad * 8;
        bf16x8 a0 = load_bf8(kp);
        bf16x8 a1 = load_bf8(kp + 32);
        bf16x8 a2 = load_bf8(kp + 16 * 64);
        bf16x8 a3 = load_bf8(kp + 16 * 64 + 32);
        floatx4 s0 = (floatx4){0.f, 0.f, 0.f, 0.f};
        floatx4 s1 = (floatx4){0.f, 0.f, 0.f, 0.f};
        s0 = MFMA16(a0, bq0, s0);
        s0 = MFMA16(a1, bq1, s0);
        s1 = MFMA16(a2, bq0, s1);
        s1 = MFMA16(a3, bq1, s1);
        floatx4 r0 = *reinterpret_cast<const floatx4*>(rl + rowbase + i0 + quad * 4);
        floatx4 r1 = *reinterpret_cast<const floatx4*>(rl + rowbase + i0 + 16 + quad * 4);
        us4 p0u, p1u;
#pragma unroll
        for (int r = 0; r < 4; r++) {
            p0u[r] = f2bfbits(__expf(s0[r]) * r0[r]);
            p1u[r] = f2bfbits(__expf(s1[r]) * r1[r]);
        }
        s16x4 p0 = __builtin_bit_cast(s16x4, p0u);
        s16x4 p1 = __builtin_bit_cast(s16x4, p1u);
        // PV: A = P^T (direct from regs), B = V [k=i=quad*4+j][n=c=t*16+l15]
#pragma unroll
        for (int t = 0; t < 4; t++) {
            const __hip_bfloat16* vp = vbase + t * 16 * 4096 + i0 + quad * 4;
            s16x4 bv0 = *reinterpret_cast<const s16x4*>(vp);
            s16x4 bv1 = *reinterpret_cast<const s16x4*>(vp + 16);
            acc[t] = MFMA1K(p0, bv0, acc[t]);
            acc[t] = MFMA1K(p1, bv1, acc[t]);
        }
    }
    // reduce partial accumulators across the 8 waves
    __shared__ floatx4 redbuf[7][4][64];  // 28 KB
    if (widx > 0) {
#pragma unroll
        for (int t = 0; t < 4; t++) redbuf[widx - 1][t][lane] = acc[t];
    }
    __syncthreads();
    if (widx == 0) {
#pragma unroll
        for (int t = 0; t < 4; t++) {
#pragma unroll
            for (int w = 0; w < 7; w++) acc[t] += redbuf[w][t][lane];
            // D layout: row = j (quad*4+r), col = c (l15). Store attT[n][c][j].
            float* op = attT + (n * 64 + t * 16 + l15) * 4096 + jbase + quad * 4;
            *reinterpret_cast<floatx4*>(op) = acc[t];
        }
    }
}

// ---------------------------------------------------------------------------
// K4: final sepconv + residual (all fp32 I/O).
// att_reshaped[n,h,w,cc] = attT[n][h][w*64+cc]  (raw-reshape coincidence).
// out[n,h,w,co] = g * (b_a[co] + sum_cc att*dw_a[cc]*pw_a[cc][co]) + g
// ---------------------------------------------------------------------------
__global__ __launch_bounds__(256) void final_out(
    const float* __restrict__ attT, const float* __restrict__ gco,
    const float* __restrict__ dwa, const float* __restrict__ pwa,
    const float* __restrict__ ba, float* __restrict__ out)
{
    int b = blockIdx.x;       // 2048 blocks
    int n = b >> 9;
    int h = (b >> 3) & 63;
    int w0 = (b & 7) << 3;
    __shared__ float g[512];
    int tid = threadIdx.x;
    const float* ap = attT + (n * 64 + h) * 4096 + w0 * 64;
    for (int jj = tid; jj < 512; jj += 256)
        g[jj] = ap[jj] * dwa[jj & 63];
    __syncthreads();
    float acc[8];
#pragma unroll
    for (int w = 0; w < 8; w++) acc[w] = 0.f;
    for (int cc = 0; cc < 64; cc++) {
        float p = pwa[cc * 256 + tid];
#pragma unroll
        for (int w = 0; w < 8; w++) acc[w] += g[w * 64 + cc] * p;
    }
    float bb = ba[tid];
#pragma unroll
    for (int w = 0; w < 8; w++) {
        int pos = (n * 64 + h) * 64 + w0 + w;
        float gv = gco[pos * 256 + tid];
        out[pos * 256 + tid] = gv * (acc[w] + bb) + gv;
    }
}

// ---------------------------------------------------------------------------
extern "C" void kernel_launch(void* const* d_in, const int* in_sizes, int n_in,
                              void* d_out, int out_size, void* d_ws, size_t ws_size,
                              hipStream_t stream) {
    const float* x   = (const float*)d_in[0];
    const float* gco = (const float*)d_in[1];
    const float* dwq = (const float*)d_in[2];
    const float* pwq = (const float*)d_in[3];
    const float* bq  = (const float*)d_in[4];
    const float* dwk = (const float*)d_in[5];
    const float* pwk = (const float*)d_in[6];
    const float* bk  = (const float*)d_in[7];
    const float* dwv = (const float*)d_in[8];
    const float* pwv = (const float*)d_in[9];
    const float* bv  = (const float*)d_in[10];
    const float* dwa = (const float*)d_in[11];
    const float* pwa = (const float*)d_in[12];
    const float* ba  = (const float*)d_in[13];
    float* out = (float*)d_out;

    char* ws = (char*)d_ws;
    __hip_bfloat16* wT = (__hip_bfloat16*)ws;                              // 98304 B
    __hip_bfloat16* qb = (__hip_bfloat16*)(ws + 98304);                    // 2 MB
    __hip_bfloat16* kb = (__hip_bfloat16*)(ws + 98304 + 2097152);          // 2 MB
    __hip_bfloat16* vt = (__hip_bfloat16*)(ws + 98304 + 2 * 2097152);      // 2 MB
    float* rl   = (float*)(ws + 98304 + 3 * 2097152);                      // 64 KB
    float* attT = (float*)(ws + 98304 + 3 * 2097152 + 65536);              // 4 MB

    prep_w<<<192, 256, 0, stream>>>(dwq, pwq, dwk, pwk, dwv, pwv, wT);
    proj_qkv<<<768, 256, 0, stream>>>(x, wT, bq, bk, bv, qb, kb, vt);
    pass1_rl<<<1024, 512, 0, stream>>>(qb, kb, rl);
    pass2_att<<<1024, 512, 0, stream>>>(qb, kb, vt, rl, attT);
    final_out<<<2048, 256, 0, stream>>>(attT, gco, dwa, pwa, ba, out);
}

// Round 6
// 221.322 us; speedup vs baseline: 1.6644x; 1.6644x over previous
//
#include <hip/hip_runtime.h>
#include <hip/hip_bf16.h>

typedef __attribute__((ext_vector_type(8))) __bf16 bf16x8;
typedef __attribute__((ext_vector_type(4))) float floatx4;
typedef __attribute__((ext_vector_type(4))) unsigned short us4;
typedef __attribute__((ext_vector_type(8))) unsigned short us8;
typedef __attribute__((ext_vector_type(4))) short s16x4;

#define MFMA16(A, B, C) __builtin_amdgcn_mfma_f32_16x16x32_bf16((A), (B), (C), 0, 0, 0)
#define MFMA1K(A, B, C) __builtin_amdgcn_mfma_f32_16x16x16bf16_1k((A), (B), (C), 0, 0, 0)

static __device__ __forceinline__ unsigned short f2bfbits(float f) {
    __hip_bfloat16 h = __float2bfloat16(f);
    union { __hip_bfloat16 h; unsigned short u; } cv;
    cv.h = h;
    return cv.u;
}
static __device__ __forceinline__ bf16x8 load_bf8(const __hip_bfloat16* p) {
    return *reinterpret_cast<const bf16x8*>(p);
}
static __device__ __forceinline__ bf16x8 cvt8(floatx4 a, floatx4 b) {
    us8 u;
#pragma unroll
    for (int i = 0; i < 4; i++) { u[i] = f2bfbits(a[i]); u[4 + i] = f2bfbits(b[i]); }
    return __builtin_bit_cast(bf16x8, u);
}

// Fragment layouts (element index within a 16-row tile, 1024 bf16 per tile):
//   qf/kf[tile][h(2)][lane(64)][e(8)]: value = M[tile*16 + (lane&15)][h*32 + (lane>>4)*8 + e]
//     -> A/B frag for 16x16x32 MFMA is a single coalesced 16B/lane load.
//   vf[tile][t(4)][lane(64)][e(4)]:    value = V[tile*16 + (lane>>4)*4 + e][t*16 + (lane&15)]
//     -> B frag for 16x16x16 MFMA1K is a coalesced 8B/lane load.

// ---------------------------------------------------------------------------
// K0: wT[p][d][c] = dw_p[c] * pw_p[c][d]   (bf16, [d][c] for B-frag loads)
// ---------------------------------------------------------------------------
__global__ __launch_bounds__(256) void prep_w(
    const float* __restrict__ dwq, const float* __restrict__ pwq,
    const float* __restrict__ dwk, const float* __restrict__ pwk,
    const float* __restrict__ dwv, const float* __restrict__ pwv,
    __hip_bfloat16* __restrict__ wT)
{
    int idx = blockIdx.x * 256 + threadIdx.x;   // < 49152
    int p = idx >> 14;
    int r = idx & 16383;
    int d = r >> 8, c = r & 255;
    const float* dw = (p == 0) ? dwq : ((p == 1) ? dwk : dwv);
    const float* pw = (p == 0) ? pwq : ((p == 1) ? pwk : pwv);
    wT[idx] = __float2bfloat16(dw[c] * pw[c * 64 + d]);
}

// ---------------------------------------------------------------------------
// K1: fused Q,K,V projection. One wave per 16-row tile (x read ONCE).
// Outputs directly in fragment order: qf/kf (scatter), vf (coalesced: the
// MFMA C-layout registers coincide with vf's frag layout).
// ---------------------------------------------------------------------------
__global__ __launch_bounds__(256) void proj_qkv(
    const float* __restrict__ x,
    const __hip_bfloat16* __restrict__ wT,
    const float* __restrict__ bqp, const float* __restrict__ bkp,
    const float* __restrict__ bvp,
    __hip_bfloat16* __restrict__ qf, __hip_bfloat16* __restrict__ kf,
    __hip_bfloat16* __restrict__ vf)
{
    int wid = blockIdx.x * 4 + (threadIdx.x >> 6);  // 0..1023 global tile
    int lane = threadIdx.x & 63;
    int l15 = lane & 15, quad = lane >> 4;
    int strip = wid << 4;

    floatx4 acc[3][4];
#pragma unroll
    for (int p = 0; p < 3; p++)
#pragma unroll
        for (int t = 0; t < 4; t++) acc[p][t] = (floatx4){0.f, 0.f, 0.f, 0.f};

    const float* xrow = x + (strip + l15) * 256 + quad * 8;
#pragma unroll
    for (int ks = 0; ks < 8; ks++) {
        floatx4 xa = *reinterpret_cast<const floatx4*>(xrow + ks * 32);
        floatx4 xb = *reinterpret_cast<const floatx4*>(xrow + ks * 32 + 4);
        bf16x8 a = cvt8(xa, xb);
#pragma unroll
        for (int p = 0; p < 3; p++)
#pragma unroll
            for (int t = 0; t < 4; t++) {
                bf16x8 b = load_bf8(wT + p * 16384 + (t * 16 + l15) * 256 + ks * 32 + quad * 8);
                acc[p][t] = MFMA16(a, b, acc[p][t]);
            }
    }
    // q,k -> frag-order scatter.  C-layout: value(m = strip + quad*4 + r, d = t*16 + l15)
#pragma unroll
    for (int p = 0; p < 2; p++) {
        __hip_bfloat16* dst = (p == 0) ? qf : kf;
        const float* bias = (p == 0) ? bqp : bkp;
#pragma unroll
        for (int t = 0; t < 4; t++) {
            float bsv = bias[t * 16 + l15];
            int off0 = wid * 1024 + (t >> 1) * 512 +
                       (((((t & 1) << 1) | (l15 >> 3)) * 16 + quad * 4) * 8) + (l15 & 7);
#pragma unroll
            for (int r = 0; r < 4; r++)
                dst[off0 + r * 8] = __float2bfloat16(acc[p][t][r] + bsv);
        }
    }
    // v -> frag-order, coalesced: dest = (wid*4 + t)*256 + lane*4 + r
#pragma unroll
    for (int t = 0; t < 4; t++) {
        float bsv = bvp[t * 16 + l15];
        us4 pk;
#pragma unroll
        for (int r = 0; r < 4; r++) pk[r] = f2bfbits(acc[2][t][r] + bsv);
        *reinterpret_cast<us4*>(vf + (wid * 4 + t) * 256 + lane * 4) = pk;
    }
}

// ---------------------------------------------------------------------------
// K2: rl[i] = 1 / sum_j exp(k_i . q_j).  512 blocks x 256. Block = 2 i-tiles
// x 2 j-halves (one wave each). All loads coalesced frag loads.
// ---------------------------------------------------------------------------
__global__ __launch_bounds__(256) void pass1_rl(
    const __hip_bfloat16* __restrict__ qf, const __hip_bfloat16* __restrict__ kf,
    float* __restrict__ rl)
{
    int b = blockIdx.x;                   // 0..511
    int w = threadIdx.x >> 6;             // 0..3
    int lane = threadIdx.x & 63;
    int l15 = lane & 15, quad = lane >> 4;
    int itg = b * 2 + (w >> 1);           // global i-tile 0..1023
    int jh = w & 1;
    int n = itg >> 8;

    const __hip_bfloat16* kp = kf + itg * 1024;
    bf16x8 a0 = load_bf8(kp + lane * 8);
    bf16x8 a1 = load_bf8(kp + 512 + lane * 8);

    float ls0 = 0.f, ls1 = 0.f, ls2 = 0.f, ls3 = 0.f;
    int jt0 = n * 256 + jh * 128;
    for (int jt = jt0; jt < jt0 + 128; jt += 2) {
        const __hip_bfloat16* qp0 = qf + jt * 1024;
        bf16x8 b0 = load_bf8(qp0 + lane * 8);
        bf16x8 b1 = load_bf8(qp0 + 512 + lane * 8);
        bf16x8 b2 = load_bf8(qp0 + 1024 + lane * 8);
        bf16x8 b3 = load_bf8(qp0 + 1536 + lane * 8);
        floatx4 s0 = (floatx4){0.f, 0.f, 0.f, 0.f};
        floatx4 s1 = (floatx4){0.f, 0.f, 0.f, 0.f};
        s0 = MFMA16(a0, b0, s0);
        s0 = MFMA16(a1, b1, s0);
        s1 = MFMA16(a0, b2, s1);
        s1 = MFMA16(a1, b3, s1);
        ls0 += __expf(s0[0]) + __expf(s1[0]);
        ls1 += __expf(s0[1]) + __expf(s1[1]);
        ls2 += __expf(s0[2]) + __expf(s1[2]);
        ls3 += __expf(s0[3]) + __expf(s1[3]);
    }
#pragma unroll
    for (int m = 1; m < 16; m <<= 1) {
        ls0 += __shfl_xor(ls0, m, 64);
        ls1 += __shfl_xor(ls1, m, 64);
        ls2 += __shfl_xor(ls2, m, 64);
        ls3 += __shfl_xor(ls3, m, 64);
    }
    __shared__ float red[4][16];
    if (l15 == 0) {
        red[w][quad * 4 + 0] = ls0;
        red[w][quad * 4 + 1] = ls1;
        red[w][quad * 4 + 2] = ls2;
        red[w][quad * 4 + 3] = ls3;
    }
    __syncthreads();
    int tid = threadIdx.x;
    if (tid < 32) {
        int sub = tid >> 4, ii = tid & 15;
        float tot = red[sub * 2][ii] + red[sub * 2 + 1][ii];
        rl[(b * 2 + sub) * 16 + ii] = 1.0f / tot;
    }
}

// ---------------------------------------------------------------------------
// K3: attT[n][c][j] partials.  512 blocks x 256: block = (i-half, n, j-group);
// 4 waves = 4 j-tiles sharing the same k/v stream (L1 reuse). All inner-loop
// loads coalesced frag loads; P stays in registers (C->A layout identity).
// ---------------------------------------------------------------------------
__global__ __launch_bounds__(256) void pass2_att(
    const __hip_bfloat16* __restrict__ qf, const __hip_bfloat16* __restrict__ kf,
    const __hip_bfloat16* __restrict__ vf, const float* __restrict__ rl,
    float* __restrict__ attp)
{
    int b = blockIdx.x;          // 0..511
    int ih = b & 1;
    int g = b >> 1;              // 0..255
    int n = g >> 6;
    int jg = g & 63;
    int w = threadIdx.x >> 6;
    int jt = jg * 4 + w;         // local j-tile 0..255
    int lane = threadIdx.x & 63;
    int l15 = lane & 15, quad = lane >> 4;

    const __hip_bfloat16* qp = qf + (n * 256 + jt) * 1024;
    bf16x8 bq0 = load_bf8(qp + lane * 8);
    bf16x8 bq1 = load_bf8(qp + 512 + lane * 8);

    floatx4 acc[4];
#pragma unroll
    for (int t = 0; t < 4; t++) acc[t] = (floatx4){0.f, 0.f, 0.f, 0.f};

    int it0 = n * 256 + ih * 128;
    for (int itg = it0; itg < it0 + 128; itg++) {
        const __hip_bfloat16* kp = kf + itg * 1024;
        bf16x8 a0 = load_bf8(kp + lane * 8);
        bf16x8 a1 = load_bf8(kp + 512 + lane * 8);
        floatx4 s = (floatx4){0.f, 0.f, 0.f, 0.f};
        s = MFMA16(a0, bq0, s);
        s = MFMA16(a1, bq1, s);
        floatx4 rv = *reinterpret_cast<const floatx4*>(rl + itg * 16 + quad * 4);
        us4 pu;
#pragma unroll
        for (int r = 0; r < 4; r++) pu[r] = f2bfbits(__expf(s[r]) * rv[r]);
        s16x4 p = __builtin_bit_cast(s16x4, pu);
        const __hip_bfloat16* vp = vf + itg * 1024;
#pragma unroll
        for (int t = 0; t < 4; t++) {
            s16x4 bv = *reinterpret_cast<const s16x4*>(vp + t * 256 + lane * 4);
            acc[t] = MFMA1K(p, bv, acc[t]);
        }
    }
    // D layout: row = j (quad*4+r), col = c (l15). Store partial attT[n][c][j].
    float* op0 = attp + ih * 1048576;
#pragma unroll
    for (int t = 0; t < 4; t++) {
        float* op = op0 + (n * 64 + t * 16 + l15) * 4096 + jt * 16 + quad * 4;
        *reinterpret_cast<floatx4*>(op) = acc[t];
    }
}

// ---------------------------------------------------------------------------
// K4: final sepconv + residual, summing the 2 i-half partials.
// att_reshaped[n,h,w,cc] = attT[n][h][w*64+cc]  (raw-reshape coincidence).
// ---------------------------------------------------------------------------
__global__ __launch_bounds__(256) void final_out(
    const float* __restrict__ attp, const float* __restrict__ gco,
    const float* __restrict__ dwa, const float* __restrict__ pwa,
    const float* __restrict__ ba, float* __restrict__ out)
{
    int b = blockIdx.x;       // 2048 blocks
    int n = b >> 9;
    int h = (b >> 3) & 63;
    int w0 = (b & 7) << 3;
    __shared__ float g[512];
    int tid = threadIdx.x;
    const float* ap0 = attp + (n * 64 + h) * 4096 + w0 * 64;
    const float* ap1 = ap0 + 1048576;
    for (int jj = tid; jj < 512; jj += 256)
        g[jj] = (ap0[jj] + ap1[jj]) * dwa[jj & 63];
    __syncthreads();
    float acc[8];
#pragma unroll
    for (int w = 0; w < 8; w++) acc[w] = 0.f;
    for (int cc = 0; cc < 64; cc++) {
        float p = pwa[cc * 256 + tid];
#pragma unroll
        for (int w = 0; w < 8; w++) acc[w] += g[w * 64 + cc] * p;
    }
    float bb = ba[tid];
#pragma unroll
    for (int w = 0; w < 8; w++) {
        int pos = (n * 64 + h) * 64 + w0 + w;
        float gv = gco[pos * 256 + tid];
        out[pos * 256 + tid] = gv * (acc[w] + bb) + gv;
    }
}

// ---------------------------------------------------------------------------
extern "C" void kernel_launch(void* const* d_in, const int* in_sizes, int n_in,
                              void* d_out, int out_size, void* d_ws, size_t ws_size,
                              hipStream_t stream) {
    const float* x   = (const float*)d_in[0];
    const float* gco = (const float*)d_in[1];
    const float* dwq = (const float*)d_in[2];
    const float* pwq = (const float*)d_in[3];
    const float* bq  = (const float*)d_in[4];
    const float* dwk = (const float*)d_in[5];
    const float* pwk = (const float*)d_in[6];
    const float* bk  = (const float*)d_in[7];
    const float* dwv = (const float*)d_in[8];
    const float* pwv = (const float*)d_in[9];
    const float* bv  = (const float*)d_in[10];
    const float* dwa = (const float*)d_in[11];
    const float* pwa = (const float*)d_in[12];
    const float* ba  = (const float*)d_in[13];
    float* out = (float*)d_out;

    char* ws = (char*)d_ws;
    __hip_bfloat16* wT = (__hip_bfloat16*)ws;                    // 98304 B
    __hip_bfloat16* qf = (__hip_bfloat16*)(ws + 98304);          // 2 MB
    __hip_bfloat16* kf = (__hip_bfloat16*)(ws + 2195456);        // 2 MB
    __hip_bfloat16* vf = (__hip_bfloat16*)(ws + 4292608);        // 2 MB
    float* rl   = (float*)(ws + 6389760);                        // 64 KB
    float* attp = (float*)(ws + 6455296);                        // 2 x 4 MB

    prep_w<<<192, 256, 0, stream>>>(dwq, pwq, dwk, pwk, dwv, pwv, wT);
    proj_qkv<<<256, 256, 0, stream>>>(x, wT, bq, bk, bv, qf, kf, vf);
    pass1_rl<<<512, 256, 0, stream>>>(qf, kf, rl);
    pass2_att<<<512, 256, 0, stream>>>(qf, kf, vf, rl, attp);
    final_out<<<2048, 256, 0, stream>>>(attp, gco, dwa, pwa, ba, out);
}

// Round 7
// 202.199 us; speedup vs baseline: 1.8218x; 1.0946x over previous
//
#include <hip/hip_runtime.h>
#include <hip/hip_bf16.h>

typedef __attribute__((ext_vector_type(8))) __bf16 bf16x8;
typedef __attribute__((ext_vector_type(4))) float floatx4;
typedef __attribute__((ext_vector_type(2))) unsigned short us2;
typedef __attribute__((ext_vector_type(4))) unsigned short us4;
typedef __attribute__((ext_vector_type(8))) unsigned short us8;
typedef __attribute__((ext_vector_type(4))) short s16x4;
typedef __attribute__((ext_vector_type(2))) unsigned int uint2v;

#define MFMA16(A, B, C) __builtin_amdgcn_mfma_f32_16x16x32_bf16((A), (B), (C), 0, 0, 0)
#define MFMA1K(A, B, C) __builtin_amdgcn_mfma_f32_16x16x16bf16_1k((A), (B), (C), 0, 0, 0)

static __device__ __forceinline__ unsigned short f2bfbits(float f) {
    __hip_bfloat16 h = __float2bfloat16(f);
    union { __hip_bfloat16 h; unsigned short u; } cv;
    cv.h = h;
    return cv.u;
}
// fast bf16 RNE (no NaN handling needed: finite, moderate values only)
static __device__ __forceinline__ unsigned int rne32(float f) {
    unsigned int u = __builtin_bit_cast(unsigned int, f);
    return u + 0x7fffu + ((u >> 16) & 1u);
}
static __device__ __forceinline__ unsigned short rne16(float f) {
    return (unsigned short)(rne32(f) >> 16);
}
// pack 4 floats -> 4 bf16 via v_perm pair-merge
static __device__ __forceinline__ s16x4 pack4(float e0, float e1, float e2, float e3) {
    unsigned int pa = __builtin_amdgcn_perm(rne32(e1), rne32(e0), 0x07060302u);
    unsigned int pb = __builtin_amdgcn_perm(rne32(e3), rne32(e2), 0x07060302u);
    uint2v u = {pa, pb};
    return __builtin_bit_cast(s16x4, u);
}
static __device__ __forceinline__ bf16x8 load_bf8(const __hip_bfloat16* p) {
    return *reinterpret_cast<const bf16x8*>(p);
}
static __device__ __forceinline__ bf16x8 cvt8(floatx4 a, floatx4 b) {
    us8 u;
#pragma unroll
    for (int i = 0; i < 4; i++) { u[i] = rne16(a[i]); u[4 + i] = rne16(b[i]); }
    return __builtin_bit_cast(bf16x8, u);
}
static __device__ __forceinline__ float bf2f(unsigned short u) {
    unsigned int w = ((unsigned int)u) << 16;
    return __builtin_bit_cast(float, w);
}

// Fragment layouts (16-row tile = 1024 bf16):
//   qf/kf[tile][h(2)][lane(64)][e(8)]: M[tile*16 + (lane&15)][h*32 + (lane>>4)*8 + e]
//   vf/vfs[tile][t(4)][lane(64)][e(4)]: V[tile*16 + (lane>>4)*4 + e][t*16 + (lane&15)]

// ---------------------------------------------------------------------------
// K0: wT[p][d][c] = dw_p[c] * pw_p[c][d]
// ---------------------------------------------------------------------------
__global__ __launch_bounds__(256) void prep_w(
    const float* __restrict__ dwq, const float* __restrict__ pwq,
    const float* __restrict__ dwk, const float* __restrict__ pwk,
    const float* __restrict__ dwv, const float* __restrict__ pwv,
    __hip_bfloat16* __restrict__ wT)
{
    int idx = blockIdx.x * 256 + threadIdx.x;   // < 49152
    int p = idx >> 14;
    int r = idx & 16383;
    int d = r >> 8, c = r & 255;
    const float* dw = (p == 0) ? dwq : ((p == 1) ? dwk : dwv);
    const float* pw = (p == 0) ? pwq : ((p == 1) ? pwk : pwv);
    wT[idx] = __float2bfloat16(dw[c] * pw[c * 64 + d]);
}

// ---------------------------------------------------------------------------
// K1: fused Q,K,V projection (one wave per 16-row tile; x read once).
// ---------------------------------------------------------------------------
__global__ __launch_bounds__(256) void proj_qkv(
    const float* __restrict__ x,
    const __hip_bfloat16* __restrict__ wT,
    const float* __restrict__ bqp, const float* __restrict__ bkp,
    const float* __restrict__ bvp,
    __hip_bfloat16* __restrict__ qf, __hip_bfloat16* __restrict__ kf,
    __hip_bfloat16* __restrict__ vf)
{
    int wid = blockIdx.x * 4 + (threadIdx.x >> 6);  // 0..1023 global tile
    int lane = threadIdx.x & 63;
    int l15 = lane & 15, quad = lane >> 4;
    int strip = wid << 4;

    floatx4 acc[3][4];
#pragma unroll
    for (int p = 0; p < 3; p++)
#pragma unroll
        for (int t = 0; t < 4; t++) acc[p][t] = (floatx4){0.f, 0.f, 0.f, 0.f};

    const float* xrow = x + (strip + l15) * 256 + quad * 8;
#pragma unroll
    for (int ks = 0; ks < 8; ks++) {
        floatx4 xa = *reinterpret_cast<const floatx4*>(xrow + ks * 32);
        floatx4 xb = *reinterpret_cast<const floatx4*>(xrow + ks * 32 + 4);
        bf16x8 a = cvt8(xa, xb);
#pragma unroll
        for (int p = 0; p < 3; p++)
#pragma unroll
            for (int t = 0; t < 4; t++) {
                bf16x8 b = load_bf8(wT + p * 16384 + (t * 16 + l15) * 256 + ks * 32 + quad * 8);
                acc[p][t] = MFMA16(a, b, acc[p][t]);
            }
    }
    // q,k -> frag-order scatter
#pragma unroll
    for (int p = 0; p < 2; p++) {
        __hip_bfloat16* dst = (p == 0) ? qf : kf;
        const float* bias = (p == 0) ? bqp : bkp;
#pragma unroll
        for (int t = 0; t < 4; t++) {
            float bsv = bias[t * 16 + l15];
            int off0 = wid * 1024 + (t >> 1) * 512 +
                       (((((t & 1) << 1) | (l15 >> 3)) * 16 + quad * 4) * 8) + (l15 & 7);
#pragma unroll
            for (int r = 0; r < 4; r++)
                dst[off0 + r * 8] = __float2bfloat16(acc[p][t][r] + bsv);
        }
    }
    // v -> frag-order, coalesced
#pragma unroll
    for (int t = 0; t < 4; t++) {
        float bsv = bvp[t * 16 + l15];
        us4 pk;
#pragma unroll
        for (int r = 0; r < 4; r++) pk[r] = f2bfbits(acc[2][t][r] + bsv);
        *reinterpret_cast<us4*>(vf + (wid * 4 + t) * 256 + lane * 4) = pk;
    }
}

// ---------------------------------------------------------------------------
// K2: per i-tile block (1024 blocks x 512 thr = 100% cap): 8 waves split j.
// Computes rl_i = 1/sum_j exp(k_i.q_j) in LDS, then writes vfs = vf * rl
// (rl folded into V; no rl buffer, pass2 needs no per-iter rl load/mul).
// ---------------------------------------------------------------------------
__global__ __launch_bounds__(512) void pass1_rl(
    const __hip_bfloat16* __restrict__ qf, const __hip_bfloat16* __restrict__ kf,
    const __hip_bfloat16* __restrict__ vf, __hip_bfloat16* __restrict__ vfs)
{
    int itg = blockIdx.x;                 // global i-tile 0..1023
    int n = itg >> 8;
    int jw = threadIdx.x >> 6;            // 0..7
    int lane = threadIdx.x & 63;
    int l15 = lane & 15, quad = lane >> 4;

    const __hip_bfloat16* kp = kf + itg * 1024;
    bf16x8 a0 = load_bf8(kp + lane * 8);
    bf16x8 a1 = load_bf8(kp + 512 + lane * 8);

    float ls0 = 0.f, ls1 = 0.f, ls2 = 0.f, ls3 = 0.f;
    const __hip_bfloat16* qp0 = qf + (n * 256 + jw * 32) * 1024 + lane * 8;
    for (int it = 0; it < 16; it++, qp0 += 2048) {
        bf16x8 b0 = load_bf8(qp0);
        bf16x8 b1 = load_bf8(qp0 + 512);
        bf16x8 b2 = load_bf8(qp0 + 1024);
        bf16x8 b3 = load_bf8(qp0 + 1536);
        floatx4 s0 = (floatx4){0.f, 0.f, 0.f, 0.f};
        floatx4 s1 = (floatx4){0.f, 0.f, 0.f, 0.f};
        s0 = MFMA16(a0, b0, s0);
        s0 = MFMA16(a1, b1, s0);
        s1 = MFMA16(a0, b2, s1);
        s1 = MFMA16(a1, b3, s1);
        ls0 += __expf(s0[0]) + __expf(s1[0]);
        ls1 += __expf(s0[1]) + __expf(s1[1]);
        ls2 += __expf(s0[2]) + __expf(s1[2]);
        ls3 += __expf(s0[3]) + __expf(s1[3]);
    }
#pragma unroll
    for (int m = 1; m < 16; m <<= 1) {
        ls0 += __shfl_xor(ls0, m, 64);
        ls1 += __shfl_xor(ls1, m, 64);
        ls2 += __shfl_xor(ls2, m, 64);
        ls3 += __shfl_xor(ls3, m, 64);
    }
    __shared__ float red[8][16];
    __shared__ float rls[16];
    if (l15 == 0) {
        red[jw][quad * 4 + 0] = ls0;
        red[jw][quad * 4 + 1] = ls1;
        red[jw][quad * 4 + 2] = ls2;
        red[jw][quad * 4 + 3] = ls3;
    }
    __syncthreads();
    if (threadIdx.x < 16) {
        float tot = 0.f;
#pragma unroll
        for (int w = 0; w < 8; w++) tot += red[w][threadIdx.x];
        rls[threadIdx.x] = 1.0f / tot;
    }
    __syncthreads();
    // vfs[tile] = vf[tile] * rl(row). element m: row = ((m>>6)&3)*4 + (m&3)
    int m0 = threadIdx.x * 2;             // covers 0..1023
    us2 vv = *reinterpret_cast<const us2*>(reinterpret_cast<const unsigned short*>(vf) + itg * 1024 + m0);
    int r0 = ((m0 >> 6) & 3) * 4 + (m0 & 3);
    us2 ov;
    ov[0] = rne16(bf2f(vv[0]) * rls[r0]);
    ov[1] = rne16(bf2f(vv[1]) * rls[r0 + 1]);
    *reinterpret_cast<us2*>(reinterpret_cast<unsigned short*>(vfs) + itg * 1024 + m0) = ov;
}

// ---------------------------------------------------------------------------
// K3: attT partials, 2048 blocks x 256 (8192 waves = 100% cap).
// block = (j-group of 4 tiles) x (i-eighth ih); wave = 1 j-tile, 32 i-iters.
// P = exp(s) packed in-register (C->A layout identity); V pre-scaled by rl.
// Partials stored bf16: attp[ih][ (n*64+c)*4096 + j ].
// ---------------------------------------------------------------------------
__global__ __launch_bounds__(256) void pass2_att(
    const __hip_bfloat16* __restrict__ qf, const __hip_bfloat16* __restrict__ kf,
    const __hip_bfloat16* __restrict__ vfs,
    unsigned short* __restrict__ attp)
{
    int b = blockIdx.x;          // 0..2047
    int ih = b & 7;
    int g = b >> 3;              // 0..255
    int n = g >> 6;
    int jg = g & 63;
    int w = threadIdx.x >> 6;
    int jt = jg * 4 + w;         // local j-tile 0..255
    int lane = threadIdx.x & 63;
    int l15 = lane & 15, quad = lane >> 4;

    const __hip_bfloat16* qp = qf + (n * 256 + jt) * 1024;
    bf16x8 bq0 = load_bf8(qp + lane * 8);
    bf16x8 bq1 = load_bf8(qp + 512 + lane * 8);

    floatx4 acc[4];
#pragma unroll
    for (int t = 0; t < 4; t++) acc[t] = (floatx4){0.f, 0.f, 0.f, 0.f};

    int it0 = n * 256 + ih * 32;
    const __hip_bfloat16* kp = kf + it0 * 1024 + lane * 8;
    const __hip_bfloat16* vp = vfs + it0 * 1024;
    for (int it = 0; it < 32; it++, kp += 1024, vp += 1024) {
        bf16x8 a0 = load_bf8(kp);
        bf16x8 a1 = load_bf8(kp + 512);
        floatx4 s = (floatx4){0.f, 0.f, 0.f, 0.f};
        s = MFMA16(a0, bq0, s);
        s = MFMA16(a1, bq1, s);
        s16x4 p = pack4(__expf(s[0]), __expf(s[1]), __expf(s[2]), __expf(s[3]));
#pragma unroll
        for (int t = 0; t < 4; t++) {
            s16x4 bv = *reinterpret_cast<const s16x4*>(vp + t * 256 + lane * 4);
            acc[t] = MFMA1K(p, bv, acc[t]);
        }
    }
    // D layout: row = j (quad*4+r), col = c (l15). bf16 partial store.
    unsigned short* op0 = attp + ih * 1048576;
#pragma unroll
    for (int t = 0; t < 4; t++) {
        s16x4 pk = pack4(acc[t][0], acc[t][1], acc[t][2], acc[t][3]);
        unsigned short* op = op0 + (n * 64 + t * 16 + l15) * 4096 + jt * 16 + quad * 4;
        *reinterpret_cast<s16x4*>(op) = pk;
    }
}

// ---------------------------------------------------------------------------
// K4: final sepconv + residual, summing 8 bf16 i-partials.
// att_reshaped[n,h,w,cc] = attT[n][h][w*64+cc]  (raw-reshape coincidence).
// ---------------------------------------------------------------------------
__global__ __launch_bounds__(256) void final_out(
    const unsigned short* __restrict__ attp, const float* __restrict__ gco,
    const float* __restrict__ dwa, const float* __restrict__ pwa,
    const float* __restrict__ ba, float* __restrict__ out)
{
    int b = blockIdx.x;       // 2048 blocks
    int n = b >> 9;
    int hh = (b >> 3) & 63;
    int w0 = (b & 7) << 3;
    __shared__ float g[512];
    int tid = threadIdx.x;
    const unsigned short* ap = attp + (n * 64 + hh) * 4096 + w0 * 64;
    for (int jj = tid; jj < 512; jj += 256) {
        float v = 0.f;
#pragma unroll
        for (int ph = 0; ph < 8; ph++) v += bf2f(ap[ph * 1048576 + jj]);
        g[jj] = v * dwa[jj & 63];
    }
    __syncthreads();
    float acc[8];
#pragma unroll
    for (int w = 0; w < 8; w++) acc[w] = 0.f;
    for (int cc = 0; cc < 64; cc++) {
        float p = pwa[cc * 256 + tid];
#pragma unroll
        for (int w = 0; w < 8; w++) acc[w] += g[w * 64 + cc] * p;
    }
    float bb = ba[tid];
#pragma unroll
    for (int w = 0; w < 8; w++) {
        int pos = (n * 64 + hh) * 64 + w0 + w;
        float gv = gco[pos * 256 + tid];
        out[pos * 256 + tid] = gv * (acc[w] + bb) + gv;
    }
}

// ---------------------------------------------------------------------------
extern "C" void kernel_launch(void* const* d_in, const int* in_sizes, int n_in,
                              void* d_out, int out_size, void* d_ws, size_t ws_size,
                              hipStream_t stream) {
    const float* x   = (const float*)d_in[0];
    const float* gco = (const float*)d_in[1];
    const float* dwq = (const float*)d_in[2];
    const float* pwq = (const float*)d_in[3];
    const float* bq  = (const float*)d_in[4];
    const float* dwk = (const float*)d_in[5];
    const float* pwk = (const float*)d_in[6];
    const float* bk  = (const float*)d_in[7];
    const float* dwv = (const float*)d_in[8];
    const float* pwv = (const float*)d_in[9];
    const float* bv  = (const float*)d_in[10];
    const float* dwa = (const float*)d_in[11];
    const float* pwa = (const float*)d_in[12];
    const float* ba  = (const float*)d_in[13];
    float* out = (float*)d_out;

    char* ws = (char*)d_ws;
    __hip_bfloat16* wT  = (__hip_bfloat16*)ws;                    // 98304 B
    __hip_bfloat16* qf  = (__hip_bfloat16*)(ws + 98304);          // 2 MB
    __hip_bfloat16* kf  = (__hip_bfloat16*)(ws + 2195456);        // 2 MB
    __hip_bfloat16* vf  = (__hip_bfloat16*)(ws + 4292608);        // 2 MB
    __hip_bfloat16* vfs = (__hip_bfloat16*)(ws + 6389760);        // 2 MB
    unsigned short* attp = (unsigned short*)(ws + 8486912);       // 8 x 2 MB bf16

    prep_w<<<192, 256, 0, stream>>>(dwq, pwq, dwk, pwk, dwv, pwv, wT);
    proj_qkv<<<256, 256, 0, stream>>>(x, wT, bq, bk, bv, qf, kf, vf);
    pass1_rl<<<1024, 512, 0, stream>>>(qf, kf, vf, vfs);
    pass2_att<<<2048, 256, 0, stream>>>(qf, kf, vfs, attp);
    final_out<<<2048, 256, 0, stream>>>(attp, gco, dwa, pwa, ba, out);
}

// Round 8
// 182.570 us; speedup vs baseline: 2.0176x; 1.1075x over previous
//
#include <hip/hip_runtime.h>
#include <hip/hip_bf16.h>

typedef __attribute__((ext_vector_type(8))) __bf16 bf16x8;
typedef __attribute__((ext_vector_type(4))) float floatx4;
typedef __attribute__((ext_vector_type(4))) unsigned short us4;
typedef __attribute__((ext_vector_type(8))) unsigned short us8;
typedef __attribute__((ext_vector_type(4))) short s16x4;
typedef __attribute__((ext_vector_type(2))) unsigned int uint2v;

#define MFMA16(A, B, C) __builtin_amdgcn_mfma_f32_16x16x32_bf16((A), (B), (C), 0, 0, 0)
#define MFMA1K(A, B, C) __builtin_amdgcn_mfma_f32_16x16x16bf16_1k((A), (B), (C), 0, 0, 0)

static __device__ __forceinline__ unsigned short f2bfbits(float f) {
    __hip_bfloat16 h = __float2bfloat16(f);
    union { __hip_bfloat16 h; unsigned short u; } cv;
    cv.h = h;
    return cv.u;
}
// fast bf16 RNE (finite moderate values only)
static __device__ __forceinline__ unsigned int rne32(float f) {
    unsigned int u = __builtin_bit_cast(unsigned int, f);
    return u + 0x7fffu + ((u >> 16) & 1u);
}
static __device__ __forceinline__ unsigned short rne16(float f) {
    return (unsigned short)(rne32(f) >> 16);
}
static __device__ __forceinline__ s16x4 pack4(float e0, float e1, float e2, float e3) {
    unsigned int pa = __builtin_amdgcn_perm(rne32(e1), rne32(e0), 0x07060302u);
    unsigned int pb = __builtin_amdgcn_perm(rne32(e3), rne32(e2), 0x07060302u);
    uint2v u = {pa, pb};
    return __builtin_bit_cast(s16x4, u);
}
static __device__ __forceinline__ bf16x8 load_bf8(const __hip_bfloat16* p) {
    return *reinterpret_cast<const bf16x8*>(p);
}
static __device__ __forceinline__ bf16x8 cvt8(floatx4 a, floatx4 b) {
    us8 u;
#pragma unroll
    for (int i = 0; i < 4; i++) { u[i] = rne16(a[i]); u[4 + i] = rne16(b[i]); }
    return __builtin_bit_cast(bf16x8, u);
}
static __device__ __forceinline__ float bf2f(unsigned short u) {
    unsigned int w = ((unsigned int)u) << 16;
    return __builtin_bit_cast(float, w);
}

// Fragment layouts (16-row tile = 1024 bf16):
//   qf/kf[tile][h(2)][lane(64)][e(8)]: M[tile*16 + (lane&15)][h*32 + (lane>>4)*8 + e]
//   vf/vfs[tile][t(4)][lane(64)][e(4)]: V[tile*16 + (lane>>4)*4 + e][t*16 + (lane&15)]

// ---------------------------------------------------------------------------
// K0: wT[p][d][c] = dw_p[c] * pw_p[c][d]
// ---------------------------------------------------------------------------
__global__ __launch_bounds__(256) void prep_w(
    const float* __restrict__ dwq, const float* __restrict__ pwq,
    const float* __restrict__ dwk, const float* __restrict__ pwk,
    const float* __restrict__ dwv, const float* __restrict__ pwv,
    __hip_bfloat16* __restrict__ wT)
{
    int idx = blockIdx.x * 256 + threadIdx.x;   // < 49152
    int p = idx >> 14;
    int r = idx & 16383;
    int d = r >> 8, c = r & 255;
    const float* dw = (p == 0) ? dwq : ((p == 1) ? dwk : dwv);
    const float* pw = (p == 0) ? pwq : ((p == 1) ? pwk : pwv);
    wT[idx] = __float2bfloat16(dw[c] * pw[c * 64 + d]);
}

// ---------------------------------------------------------------------------
// K1: QKV projection, one wave per (tile, proj): 768 blocks (3x parallelism;
// x re-reads are L3-resident).
// ---------------------------------------------------------------------------
__global__ __launch_bounds__(256) void proj_qkv(
    const float* __restrict__ x,
    const __hip_bfloat16* __restrict__ wT,
    const float* __restrict__ bqp, const float* __restrict__ bkp,
    const float* __restrict__ bvp,
    __hip_bfloat16* __restrict__ qf, __hip_bfloat16* __restrict__ kf,
    __hip_bfloat16* __restrict__ vf)
{
    int wg = blockIdx.x * 4 + (threadIdx.x >> 6);   // 0..3071
    int p = wg >> 10;                                // 0=q 1=k 2=v
    int wid = wg & 1023;                             // tile
    int lane = threadIdx.x & 63;
    int l15 = lane & 15, quad = lane >> 4;
    int strip = wid << 4;

    floatx4 acc[4];
#pragma unroll
    for (int t = 0; t < 4; t++) acc[t] = (floatx4){0.f, 0.f, 0.f, 0.f};

    const float* xrow = x + (strip + l15) * 256 + quad * 8;
    const __hip_bfloat16* wp = wT + p * 16384;
#pragma unroll
    for (int ks = 0; ks < 8; ks++) {
        floatx4 xa = *reinterpret_cast<const floatx4*>(xrow + ks * 32);
        floatx4 xb = *reinterpret_cast<const floatx4*>(xrow + ks * 32 + 4);
        bf16x8 a = cvt8(xa, xb);
#pragma unroll
        for (int t = 0; t < 4; t++) {
            bf16x8 b = load_bf8(wp + (t * 16 + l15) * 256 + ks * 32 + quad * 8);
            acc[t] = MFMA16(a, b, acc[t]);
        }
    }
    if (p < 2) {
        __hip_bfloat16* dst = (p == 0) ? qf : kf;
        const float* bias = (p == 0) ? bqp : bkp;
#pragma unroll
        for (int t = 0; t < 4; t++) {
            float bsv = bias[t * 16 + l15];
            int off0 = wid * 1024 + (t >> 1) * 512 +
                       (((((t & 1) << 1) | (l15 >> 3)) * 16 + quad * 4) * 8) + (l15 & 7);
#pragma unroll
            for (int r = 0; r < 4; r++)
                dst[off0 + r * 8] = __float2bfloat16(acc[t][r] + bsv);
        }
    } else {
#pragma unroll
        for (int t = 0; t < 4; t++) {
            float bsv = bvp[t * 16 + l15];
            us4 pk;
#pragma unroll
            for (int r = 0; r < 4; r++) pk[r] = f2bfbits(acc[t][r] + bsv);
            *reinterpret_cast<us4*>(vf + (wid * 4 + t) * 256 + lane * 4) = pk;
        }
    }
}

// ---------------------------------------------------------------------------
// K2: 512 blocks x 512 thr; block = 2 i-tiles (qf traffic halved), 8 waves
// split j; each iter: 4 q loads -> 8 MFMA16 (4 indep chains) + 16 exp.
// Tail: rl computed in LDS, folded into vfs = vf * rl.
// ---------------------------------------------------------------------------
__global__ __launch_bounds__(512) void pass1_rl(
    const __hip_bfloat16* __restrict__ qf, const __hip_bfloat16* __restrict__ kf,
    const __hip_bfloat16* __restrict__ vf, __hip_bfloat16* __restrict__ vfs)
{
    int itg0 = blockIdx.x * 2;            // i-tiles itg0, itg0+1 (same n)
    int n = itg0 >> 8;
    int jw = threadIdx.x >> 6;            // 0..7
    int lane = threadIdx.x & 63;
    int l15 = lane & 15, quad = lane >> 4;

    const __hip_bfloat16* kp = kf + itg0 * 1024 + lane * 8;
    bf16x8 a0 = load_bf8(kp);
    bf16x8 a1 = load_bf8(kp + 512);
    bf16x8 a2 = load_bf8(kp + 1024);
    bf16x8 a3 = load_bf8(kp + 1536);

    floatx4 lsA = (floatx4){0.f, 0.f, 0.f, 0.f};
    floatx4 lsB = (floatx4){0.f, 0.f, 0.f, 0.f};
    const __hip_bfloat16* qp0 = qf + (n * 256 + jw * 32) * 1024 + lane * 8;
    for (int it = 0; it < 16; it++, qp0 += 2048) {
        bf16x8 b0 = load_bf8(qp0);
        bf16x8 b1 = load_bf8(qp0 + 512);
        bf16x8 b2 = load_bf8(qp0 + 1024);
        bf16x8 b3 = load_bf8(qp0 + 1536);
        floatx4 z = (floatx4){0.f, 0.f, 0.f, 0.f};
        floatx4 sA0 = MFMA16(a1, b1, MFMA16(a0, b0, z));
        floatx4 sA1 = MFMA16(a1, b3, MFMA16(a0, b2, z));
        floatx4 sB0 = MFMA16(a3, b1, MFMA16(a2, b0, z));
        floatx4 sB1 = MFMA16(a3, b3, MFMA16(a2, b2, z));
#pragma unroll
        for (int r = 0; r < 4; r++) {
            lsA[r] += __expf(sA0[r]) + __expf(sA1[r]);
            lsB[r] += __expf(sB0[r]) + __expf(sB1[r]);
        }
    }
#pragma unroll
    for (int m = 1; m < 16; m <<= 1) {
#pragma unroll
        for (int r = 0; r < 4; r++) {
            lsA[r] += __shfl_xor(lsA[r], m, 64);
            lsB[r] += __shfl_xor(lsB[r], m, 64);
        }
    }
    __shared__ float red[8][32];
    __shared__ float rls[32];
    if (l15 == 0) {
#pragma unroll
        for (int r = 0; r < 4; r++) {
            red[jw][quad * 4 + r] = lsA[r];
            red[jw][16 + quad * 4 + r] = lsB[r];
        }
    }
    __syncthreads();
    if (threadIdx.x < 32) {
        float tot = 0.f;
#pragma unroll
        for (int w = 0; w < 8; w++) tot += red[w][threadIdx.x];
        rls[threadIdx.x] = 1.0f / tot;
    }
    __syncthreads();
    // vfs = vf * rl(row); elem m in tile: row = ((m>>6)&3)*4 + (m&3)
    int m0 = threadIdx.x * 4;             // 0..2044, covers 2 tiles
    int toff = m0 >> 10;                  // 0/1
    int mm = m0 & 1023;                   // aligned to 4 -> rows consecutive
    int rb = toff * 16 + ((mm >> 6) & 3) * 4;
    const unsigned short* vin = reinterpret_cast<const unsigned short*>(vf) + itg0 * 1024 + m0;
    us4 vv = *reinterpret_cast<const us4*>(vin);
    us4 ov;
#pragma unroll
    for (int r = 0; r < 4; r++) ov[r] = rne16(bf2f(vv[r]) * rls[rb + r]);
    *reinterpret_cast<us4*>(reinterpret_cast<unsigned short*>(vfs) + itg0 * 1024 + m0) = ov;
}

// ---------------------------------------------------------------------------
// K3: attT partials. 1024 blocks x 256; block = (n, ih of 8, jg of 8 tiles);
// wave = 2 j-tiles, 32 i-iters. Per iter: 6 loads -> 4 indep MFMA16 +
// 8 MFMA1K (vfs loads shared across both j-tiles); S split-summed to break
// the accumulator chain. P in-register (C->A identity), V pre-scaled by rl.
// ---------------------------------------------------------------------------
__global__ __launch_bounds__(256) void pass2_att(
    const __hip_bfloat16* __restrict__ qf, const __hip_bfloat16* __restrict__ kf,
    const __hip_bfloat16* __restrict__ vfs,
    unsigned short* __restrict__ attp)
{
    int b = blockIdx.x;          // 0..1023
    int ih = b & 7;
    int g = b >> 3;              // 0..127
    int n = g >> 5;
    int jg = g & 31;
    int w = threadIdx.x >> 6;
    int jt0 = jg * 8 + w * 2;    // local j-tiles jt0, jt0+1
    int lane = threadIdx.x & 63;
    int l15 = lane & 15, quad = lane >> 4;

    const __hip_bfloat16* qp = qf + (n * 256 + jt0) * 1024 + lane * 8;
    bf16x8 bq00 = load_bf8(qp);
    bf16x8 bq01 = load_bf8(qp + 512);
    bf16x8 bq10 = load_bf8(qp + 1024);
    bf16x8 bq11 = load_bf8(qp + 1536);

    floatx4 acc0[4], acc1[4];
#pragma unroll
    for (int t = 0; t < 4; t++) {
        acc0[t] = (floatx4){0.f, 0.f, 0.f, 0.f};
        acc1[t] = (floatx4){0.f, 0.f, 0.f, 0.f};
    }

    int it0 = n * 256 + ih * 32;
    const __hip_bfloat16* kp = kf + it0 * 1024 + lane * 8;
    const __hip_bfloat16* vp = vfs + it0 * 1024;
    for (int it = 0; it < 32; it++, kp += 1024, vp += 1024) {
        bf16x8 a0 = load_bf8(kp);
        bf16x8 a1 = load_bf8(kp + 512);
        floatx4 z = (floatx4){0.f, 0.f, 0.f, 0.f};
        floatx4 s0a = MFMA16(a0, bq00, z);
        floatx4 s0b = MFMA16(a1, bq01, z);
        floatx4 s1a = MFMA16(a0, bq10, z);
        floatx4 s1b = MFMA16(a1, bq11, z);
        floatx4 s0 = s0a + s0b;
        floatx4 s1 = s1a + s1b;
        s16x4 p0 = pack4(__expf(s0[0]), __expf(s0[1]), __expf(s0[2]), __expf(s0[3]));
        s16x4 p1 = pack4(__expf(s1[0]), __expf(s1[1]), __expf(s1[2]), __expf(s1[3]));
#pragma unroll
        for (int t = 0; t < 4; t++) {
            s16x4 bv = *reinterpret_cast<const s16x4*>(vp + t * 256 + lane * 4);
            acc0[t] = MFMA1K(p0, bv, acc0[t]);
            acc1[t] = MFMA1K(p1, bv, acc1[t]);
        }
    }
    unsigned short* op0 = attp + ih * 1048576;
#pragma unroll
    for (int t = 0; t < 4; t++) {
        s16x4 k0 = pack4(acc0[t][0], acc0[t][1], acc0[t][2], acc0[t][3]);
        s16x4 k1 = pack4(acc1[t][0], acc1[t][1], acc1[t][2], acc1[t][3]);
        unsigned short* op = op0 + (n * 64 + t * 16 + l15) * 4096 + jt0 * 16 + quad * 4;
        *reinterpret_cast<s16x4*>(op) = k0;
        *reinterpret_cast<s16x4*>(op + 16) = k1;
    }
}

// ---------------------------------------------------------------------------
// K4: final sepconv + residual, summing 8 bf16 i-partials.
// ---------------------------------------------------------------------------
__global__ __launch_bounds__(256) void final_out(
    const unsigned short* __restrict__ attp, const float* __restrict__ gco,
    const float* __restrict__ dwa, const float* __restrict__ pwa,
    const float* __restrict__ ba, float* __restrict__ out)
{
    int b = blockIdx.x;       // 2048 blocks
    int n = b >> 9;
    int hh = (b >> 3) & 63;
    int w0 = (b & 7) << 3;
    __shared__ float g[512];
    int tid = threadIdx.x;
    const unsigned short* ap = attp + (n * 64 + hh) * 4096 + w0 * 64;
    for (int jj = tid; jj < 512; jj += 256) {
        float v = 0.f;
#pragma unroll
        for (int ph = 0; ph < 8; ph++) v += bf2f(ap[ph * 1048576 + jj]);
        g[jj] = v * dwa[jj & 63];
    }
    __syncthreads();
    float acc[8];
#pragma unroll
    for (int w = 0; w < 8; w++) acc[w] = 0.f;
    for (int cc = 0; cc < 64; cc++) {
        float p = pwa[cc * 256 + tid];
#pragma unroll
        for (int w = 0; w < 8; w++) acc[w] += g[w * 64 + cc] * p;
    }
    float bb = ba[tid];
#pragma unroll
    for (int w = 0; w < 8; w++) {
        int pos = (n * 64 + hh) * 64 + w0 + w;
        float gv = gco[pos * 256 + tid];
        out[pos * 256 + tid] = gv * (acc[w] + bb) + gv;
    }
}

// ---------------------------------------------------------------------------
extern "C" void kernel_launch(void* const* d_in, const int* in_sizes, int n_in,
                              void* d_out, int out_size, void* d_ws, size_t ws_size,
                              hipStream_t stream) {
    const float* x   = (const float*)d_in[0];
    const float* gco = (const float*)d_in[1];
    const float* dwq = (const float*)d_in[2];
    const float* pwq = (const float*)d_in[3];
    const float* bq  = (const float*)d_in[4];
    const float* dwk = (const float*)d_in[5];
    const float* pwk = (const float*)d_in[6];
    const float* bk  = (const float*)d_in[7];
    const float* dwv = (const float*)d_in[8];
    const float* pwv = (const float*)d_in[9];
    const float* bv  = (const float*)d_in[10];
    const float* dwa = (const float*)d_in[11];
    const float* pwa = (const float*)d_in[12];
    const float* ba  = (const float*)d_in[13];
    float* out = (float*)d_out;

    char* ws = (char*)d_ws;
    __hip_bfloat16* wT  = (__hip_bfloat16*)ws;                    // 98304 B
    __hip_bfloat16* qf  = (__hip_bfloat16*)(ws + 98304);          // 2 MB
    __hip_bfloat16* kf  = (__hip_bfloat16*)(ws + 2195456);        // 2 MB
    __hip_bfloat16* vf  = (__hip_bfloat16*)(ws + 4292608);        // 2 MB
    __hip_bfloat16* vfs = (__hip_bfloat16*)(ws + 6389760);        // 2 MB
    unsigned short* attp = (unsigned short*)(ws + 8486912);       // 8 x 2 MB bf16

    prep_w<<<192, 256, 0, stream>>>(dwq, pwq, dwk, pwk, dwv, pwv, wT);
    proj_qkv<<<768, 256, 0, stream>>>(x, wT, bq, bk, bv, qf, kf, vf);
    pass1_rl<<<512, 512, 0, stream>>>(qf, kf, vf, vfs);
    pass2_att<<<1024, 256, 0, stream>>>(qf, kf, vfs, attp);
    final_out<<<2048, 256, 0, stream>>>(attp, gco, dwa, pwa, ba, out);
}

// Round 9
// 182.502 us; speedup vs baseline: 2.0184x; 1.0004x over previous
//
#include <hip/hip_runtime.h>
#include <hip/hip_bf16.h>

typedef __attribute__((ext_vector_type(8))) __bf16 bf16x8;
typedef __attribute__((ext_vector_type(2))) __bf16 bf16x2;
typedef __attribute__((ext_vector_type(4))) float floatx4;
typedef __attribute__((ext_vector_type(4))) unsigned short us4;
typedef __attribute__((ext_vector_type(8))) unsigned short us8;
typedef __attribute__((ext_vector_type(4))) short s16x4;
typedef __attribute__((ext_vector_type(2))) unsigned int uint2v;
typedef __attribute__((ext_vector_type(4))) unsigned int uint4v;

#define MFMA16(A, B, C) __builtin_amdgcn_mfma_f32_16x16x32_bf16((A), (B), (C), 0, 0, 0)
#define MFMA1K(A, B, C) __builtin_amdgcn_mfma_f32_16x16x16bf16_1k((A), (B), (C), 0, 0, 0)

#define LOG2E 1.44269504088896340736f

// exp2 via raw v_exp_f32 (input pre-scaled by log2e at projection time)
#if __has_builtin(__builtin_amdgcn_exp2f)
#define EXP2F(x) __builtin_amdgcn_exp2f(x)
#else
#define EXP2F(x) exp2f(x)
#endif

static __device__ __forceinline__ unsigned short f2bfbits(float f) {
    __hip_bfloat16 h = __float2bfloat16(f);
    union { __hip_bfloat16 h; unsigned short u; } cv;
    cv.h = h;
    return cv.u;
}
// fast bf16 RNE (finite moderate values only)
static __device__ __forceinline__ unsigned int rne32(float f) {
    unsigned int u = __builtin_bit_cast(unsigned int, f);
    return u + 0x7fffu + ((u >> 16) & 1u);
}
static __device__ __forceinline__ unsigned short rne16(float f) {
    return (unsigned short)(rne32(f) >> 16);
}

#if __has_builtin(__builtin_amdgcn_cvt_pk_bf16_f32)
// HW packed f32->bf16 (RNE): 2 inst per 4 elements
static __device__ __forceinline__ s16x4 pack4(float e0, float e1, float e2, float e3) {
    bf16x2 lo = __builtin_amdgcn_cvt_pk_bf16_f32(e0, e1);
    bf16x2 hi = __builtin_amdgcn_cvt_pk_bf16_f32(e2, e3);
    uint2v u = {__builtin_bit_cast(unsigned int, lo), __builtin_bit_cast(unsigned int, hi)};
    return __builtin_bit_cast(s16x4, u);
}
static __device__ __forceinline__ bf16x8 cvt8(floatx4 a, floatx4 b) {
    bf16x2 p0 = __builtin_amdgcn_cvt_pk_bf16_f32(a[0], a[1]);
    bf16x2 p1 = __builtin_amdgcn_cvt_pk_bf16_f32(a[2], a[3]);
    bf16x2 p2 = __builtin_amdgcn_cvt_pk_bf16_f32(b[0], b[1]);
    bf16x2 p3 = __builtin_amdgcn_cvt_pk_bf16_f32(b[2], b[3]);
    uint4v u = {__builtin_bit_cast(unsigned int, p0), __builtin_bit_cast(unsigned int, p1),
                __builtin_bit_cast(unsigned int, p2), __builtin_bit_cast(unsigned int, p3)};
    return __builtin_bit_cast(bf16x8, u);
}
#else
static __device__ __forceinline__ s16x4 pack4(float e0, float e1, float e2, float e3) {
    unsigned int pa = __builtin_amdgcn_perm(rne32(e1), rne32(e0), 0x07060302u);
    unsigned int pb = __builtin_amdgcn_perm(rne32(e3), rne32(e2), 0x07060302u);
    uint2v u = {pa, pb};
    return __builtin_bit_cast(s16x4, u);
}
static __device__ __forceinline__ bf16x8 cvt8(floatx4 a, floatx4 b) {
    us8 u;
#pragma unroll
    for (int i = 0; i < 4; i++) { u[i] = rne16(a[i]); u[4 + i] = rne16(b[i]); }
    return __builtin_bit_cast(bf16x8, u);
}
#endif

static __device__ __forceinline__ bf16x8 load_bf8(const __hip_bfloat16* p) {
    return *reinterpret_cast<const bf16x8*>(p);
}
static __device__ __forceinline__ float bf2f(unsigned short u) {
    unsigned int w = ((unsigned int)u) << 16;
    return __builtin_bit_cast(float, w);
}

// Fragment layouts (16-row tile = 1024 bf16):
//   qf/kf[tile][h(2)][lane(64)][e(8)]: M[tile*16 + (lane&15)][h*32 + (lane>>4)*8 + e]
//   vf/vfs[tile][t(4)][lane(64)][e(4)]: V[tile*16 + (lane>>4)*4 + e][t*16 + (lane&15)]
// K is pre-scaled by log2(e) (weights+bias) so exp(s) == exp2(s').

// ---------------------------------------------------------------------------
// K0: wT[p][d][c] = dw_p[c] * pw_p[c][d]  (K scaled by log2e)
// ---------------------------------------------------------------------------
__global__ __launch_bounds__(256) void prep_w(
    const float* __restrict__ dwq, const float* __restrict__ pwq,
    const float* __restrict__ dwk, const float* __restrict__ pwk,
    const float* __restrict__ dwv, const float* __restrict__ pwv,
    __hip_bfloat16* __restrict__ wT)
{
    int idx = blockIdx.x * 256 + threadIdx.x;   // < 49152
    int p = idx >> 14;
    int r = idx & 16383;
    int d = r >> 8, c = r & 255;
    const float* dw = (p == 0) ? dwq : ((p == 1) ? dwk : dwv);
    const float* pw = (p == 0) ? pwq : ((p == 1) ? pwk : pwv);
    float scale = (p == 1) ? LOG2E : 1.0f;
    wT[idx] = __float2bfloat16(dw[c] * pw[c * 64 + d] * scale);
}

// ---------------------------------------------------------------------------
// K1: QKV projection, one wave per (tile, proj): 768 blocks.
// ---------------------------------------------------------------------------
__global__ __launch_bounds__(256) void proj_qkv(
    const float* __restrict__ x,
    const __hip_bfloat16* __restrict__ wT,
    const float* __restrict__ bqp, const float* __restrict__ bkp,
    const float* __restrict__ bvp,
    __hip_bfloat16* __restrict__ qf, __hip_bfloat16* __restrict__ kf,
    __hip_bfloat16* __restrict__ vf)
{
    int wg = blockIdx.x * 4 + (threadIdx.x >> 6);   // 0..3071
    int p = wg >> 10;                                // 0=q 1=k 2=v
    int wid = wg & 1023;                             // tile
    int lane = threadIdx.x & 63;
    int l15 = lane & 15, quad = lane >> 4;
    int strip = wid << 4;

    floatx4 acc[4];
#pragma unroll
    for (int t = 0; t < 4; t++) acc[t] = (floatx4){0.f, 0.f, 0.f, 0.f};

    const float* xrow = x + (strip + l15) * 256 + quad * 8;
    const __hip_bfloat16* wp = wT + p * 16384;
#pragma unroll
    for (int ks = 0; ks < 8; ks++) {
        floatx4 xa = *reinterpret_cast<const floatx4*>(xrow + ks * 32);
        floatx4 xb = *reinterpret_cast<const floatx4*>(xrow + ks * 32 + 4);
        bf16x8 a = cvt8(xa, xb);
#pragma unroll
        for (int t = 0; t < 4; t++) {
            bf16x8 b = load_bf8(wp + (t * 16 + l15) * 256 + ks * 32 + quad * 8);
            acc[t] = MFMA16(a, b, acc[t]);
        }
    }
    if (p < 2) {
        __hip_bfloat16* dst = (p == 0) ? qf : kf;
        const float* bias = (p == 0) ? bqp : bkp;
        float bscale = (p == 1) ? LOG2E : 1.0f;
#pragma unroll
        for (int t = 0; t < 4; t++) {
            float bsv = bias[t * 16 + l15] * bscale;
            int off0 = wid * 1024 + (t >> 1) * 512 +
                       (((((t & 1) << 1) | (l15 >> 3)) * 16 + quad * 4) * 8) + (l15 & 7);
#pragma unroll
            for (int r = 0; r < 4; r++)
                dst[off0 + r * 8] = __float2bfloat16(acc[t][r] + bsv);
        }
    } else {
#pragma unroll
        for (int t = 0; t < 4; t++) {
            float bsv = bvp[t * 16 + l15];
            us4 pk;
#pragma unroll
            for (int r = 0; r < 4; r++) pk[r] = f2bfbits(acc[t][r] + bsv);
            *reinterpret_cast<us4*>(vf + (wid * 4 + t) * 256 + lane * 4) = pk;
        }
    }
}

// ---------------------------------------------------------------------------
// K2: 512 blocks x 512 thr; block = 2 i-tiles, 8 waves split j.
// rl_i = 1/sum_j exp2(s'_ij); tail writes vfs = vf * rl.
// ---------------------------------------------------------------------------
__global__ __launch_bounds__(512) void pass1_rl(
    const __hip_bfloat16* __restrict__ qf, const __hip_bfloat16* __restrict__ kf,
    const __hip_bfloat16* __restrict__ vf, __hip_bfloat16* __restrict__ vfs)
{
    int itg0 = blockIdx.x * 2;            // i-tiles itg0, itg0+1 (same n)
    int n = itg0 >> 8;
    int jw = threadIdx.x >> 6;            // 0..7
    int lane = threadIdx.x & 63;
    int l15 = lane & 15, quad = lane >> 4;

    const __hip_bfloat16* kp = kf + itg0 * 1024 + lane * 8;
    bf16x8 a0 = load_bf8(kp);
    bf16x8 a1 = load_bf8(kp + 512);
    bf16x8 a2 = load_bf8(kp + 1024);
    bf16x8 a3 = load_bf8(kp + 1536);

    floatx4 lsA = (floatx4){0.f, 0.f, 0.f, 0.f};
    floatx4 lsB = (floatx4){0.f, 0.f, 0.f, 0.f};
    const __hip_bfloat16* qp0 = qf + (n * 256 + jw * 32) * 1024 + lane * 8;
    for (int it = 0; it < 16; it++, qp0 += 2048) {
        bf16x8 b0 = load_bf8(qp0);
        bf16x8 b1 = load_bf8(qp0 + 512);
        bf16x8 b2 = load_bf8(qp0 + 1024);
        bf16x8 b3 = load_bf8(qp0 + 1536);
        floatx4 z = (floatx4){0.f, 0.f, 0.f, 0.f};
        floatx4 sA0 = MFMA16(a1, b1, MFMA16(a0, b0, z));
        floatx4 sA1 = MFMA16(a1, b3, MFMA16(a0, b2, z));
        floatx4 sB0 = MFMA16(a3, b1, MFMA16(a2, b0, z));
        floatx4 sB1 = MFMA16(a3, b3, MFMA16(a2, b2, z));
#pragma unroll
        for (int r = 0; r < 4; r++) {
            lsA[r] += EXP2F(sA0[r]) + EXP2F(sA1[r]);
            lsB[r] += EXP2F(sB0[r]) + EXP2F(sB1[r]);
        }
    }
#pragma unroll
    for (int m = 1; m < 16; m <<= 1) {
#pragma unroll
        for (int r = 0; r < 4; r++) {
            lsA[r] += __shfl_xor(lsA[r], m, 64);
            lsB[r] += __shfl_xor(lsB[r], m, 64);
        }
    }
    __shared__ float red[8][32];
    __shared__ float rls[32];
    if (l15 == 0) {
#pragma unroll
        for (int r = 0; r < 4; r++) {
            red[jw][quad * 4 + r] = lsA[r];
            red[jw][16 + quad * 4 + r] = lsB[r];
        }
    }
    __syncthreads();
    if (threadIdx.x < 32) {
        float tot = 0.f;
#pragma unroll
        for (int w = 0; w < 8; w++) tot += red[w][threadIdx.x];
        rls[threadIdx.x] = 1.0f / tot;
    }
    __syncthreads();
    // vfs = vf * rl(row); elem m in tile: row = ((m>>6)&3)*4 + (m&3)
    int m0 = threadIdx.x * 4;             // 0..2044, covers 2 tiles
    int toff = m0 >> 10;                  // 0/1
    int mm = m0 & 1023;                   // aligned to 4 -> rows consecutive
    int rb = toff * 16 + ((mm >> 6) & 3) * 4;
    const unsigned short* vin = reinterpret_cast<const unsigned short*>(vf) + itg0 * 1024 + m0;
    us4 vv = *reinterpret_cast<const us4*>(vin);
    us4 ov;
#pragma unroll
    for (int r = 0; r < 4; r++) ov[r] = rne16(bf2f(vv[r]) * rls[rb + r]);
    *reinterpret_cast<us4*>(reinterpret_cast<unsigned short*>(vfs) + itg0 * 1024 + m0) = ov;
}

// ---------------------------------------------------------------------------
// K3: attT partials. 1024 blocks x 256; wave = 2 j-tiles, 32 i-iters.
// P = exp2(s') packed in-register (C->A identity); V pre-scaled by rl.
// ---------------------------------------------------------------------------
__global__ __launch_bounds__(256) void pass2_att(
    const __hip_bfloat16* __restrict__ qf, const __hip_bfloat16* __restrict__ kf,
    const __hip_bfloat16* __restrict__ vfs,
    unsigned short* __restrict__ attp)
{
    int b = blockIdx.x;          // 0..1023
    int ih = b & 7;
    int g = b >> 3;              // 0..127
    int n = g >> 5;
    int jg = g & 31;
    int w = threadIdx.x >> 6;
    int jt0 = jg * 8 + w * 2;    // local j-tiles jt0, jt0+1
    int lane = threadIdx.x & 63;
    int l15 = lane & 15, quad = lane >> 4;

    const __hip_bfloat16* qp = qf + (n * 256 + jt0) * 1024 + lane * 8;
    bf16x8 bq00 = load_bf8(qp);
    bf16x8 bq01 = load_bf8(qp + 512);
    bf16x8 bq10 = load_bf8(qp + 1024);
    bf16x8 bq11 = load_bf8(qp + 1536);

    floatx4 acc0[4], acc1[4];
#pragma unroll
    for (int t = 0; t < 4; t++) {
        acc0[t] = (floatx4){0.f, 0.f, 0.f, 0.f};
        acc1[t] = (floatx4){0.f, 0.f, 0.f, 0.f};
    }

    int it0 = n * 256 + ih * 32;
    const __hip_bfloat16* kp = kf + it0 * 1024 + lane * 8;
    const __hip_bfloat16* vp = vfs + it0 * 1024;
    for (int it = 0; it < 32; it++, kp += 1024, vp += 1024) {
        bf16x8 a0 = load_bf8(kp);
        bf16x8 a1 = load_bf8(kp + 512);
        floatx4 z = (floatx4){0.f, 0.f, 0.f, 0.f};
        floatx4 s0a = MFMA16(a0, bq00, z);
        floatx4 s0b = MFMA16(a1, bq01, z);
        floatx4 s1a = MFMA16(a0, bq10, z);
        floatx4 s1b = MFMA16(a1, bq11, z);
        floatx4 s0 = s0a + s0b;
        floatx4 s1 = s1a + s1b;
        s16x4 p0 = pack4(EXP2F(s0[0]), EXP2F(s0[1]), EXP2F(s0[2]), EXP2F(s0[3]));
        s16x4 p1 = pack4(EXP2F(s1[0]), EXP2F(s1[1]), EXP2F(s1[2]), EXP2F(s1[3]));
#pragma unroll
        for (int t = 0; t < 4; t++) {
            s16x4 bv = *reinterpret_cast<const s16x4*>(vp + t * 256 + lane * 4);
            acc0[t] = MFMA1K(p0, bv, acc0[t]);
            acc1[t] = MFMA1K(p1, bv, acc1[t]);
        }
    }
    unsigned short* op0 = attp + ih * 1048576;
#pragma unroll
    for (int t = 0; t < 4; t++) {
        s16x4 k0 = pack4(acc0[t][0], acc0[t][1], acc0[t][2], acc0[t][3]);
        s16x4 k1 = pack4(acc1[t][0], acc1[t][1], acc1[t][2], acc1[t][3]);
        unsigned short* op = op0 + (n * 64 + t * 16 + l15) * 4096 + jt0 * 16 + quad * 4;
        *reinterpret_cast<s16x4*>(op) = k0;
        *reinterpret_cast<s16x4*>(op + 16) = k1;
    }
}

// ---------------------------------------------------------------------------
// K4: final sepconv + residual, summing 8 bf16 i-partials.
// ---------------------------------------------------------------------------
__global__ __launch_bounds__(256) void final_out(
    const unsigned short* __restrict__ attp, const float* __restrict__ gco,
    const float* __restrict__ dwa, const float* __restrict__ pwa,
    const float* __restrict__ ba, float* __restrict__ out)
{
    int b = blockIdx.x;       // 2048 blocks
    int n = b >> 9;
    int hh = (b >> 3) & 63;
    int w0 = (b & 7) << 3;
    __shared__ float g[512];
    int tid = threadIdx.x;
    const unsigned short* ap = attp + (n * 64 + hh) * 4096 + w0 * 64;
    for (int jj = tid; jj < 512; jj += 256) {
        float v = 0.f;
#pragma unroll
        for (int ph = 0; ph < 8; ph++) v += bf2f(ap[ph * 1048576 + jj]);
        g[jj] = v * dwa[jj & 63];
    }
    __syncthreads();
    float acc[8];
#pragma unroll
    for (int w = 0; w < 8; w++) acc[w] = 0.f;
    for (int cc = 0; cc < 64; cc++) {
        float p = pwa[cc * 256 + tid];
#pragma unroll
        for (int w = 0; w < 8; w++) acc[w] += g[w * 64 + cc] * p;
    }
    float bb = ba[tid];
#pragma unroll
    for (int w = 0; w < 8; w++) {
        int pos = (n * 64 + hh) * 64 + w0 + w;
        float gv = gco[pos * 256 + tid];
        out[pos * 256 + tid] = gv * (acc[w] + bb) + gv;
    }
}

// ---------------------------------------------------------------------------
extern "C" void kernel_launch(void* const* d_in, const int* in_sizes, int n_in,
                              void* d_out, int out_size, void* d_ws, size_t ws_size,
                              hipStream_t stream) {
    const float* x   = (const float*)d_in[0];
    const float* gco = (const float*)d_in[1];
    const float* dwq = (const float*)d_in[2];
    const float* pwq = (const float*)d_in[3];
    const float* bq  = (const float*)d_in[4];
    const float* dwk = (const float*)d_in[5];
    const float* pwk = (const float*)d_in[6];
    const float* bk  = (const float*)d_in[7];
    const float* dwv = (const float*)d_in[8];
    const float* pwv = (const float*)d_in[9];
    const float* bv  = (const float*)d_in[10];
    const float* dwa = (const float*)d_in[11];
    const float* pwa = (const float*)d_in[12];
    const float* ba  = (const float*)d_in[13];
    float* out = (float*)d_out;

    char* ws = (char*)d_ws;
    __hip_bfloat16* wT  = (__hip_bfloat16*)ws;                    // 98304 B
    __hip_bfloat16* qf  = (__hip_bfloat16*)(ws + 98304);          // 2 MB
    __hip_bfloat16* kf  = (__hip_bfloat16*)(ws + 2195456);        // 2 MB
    __hip_bfloat16* vf  = (__hip_bfloat16*)(ws + 4292608);        // 2 MB
    __hip_bfloat16* vfs = (__hip_bfloat16*)(ws + 6389760);        // 2 MB
    unsigned short* attp = (unsigned short*)(ws + 8486912);       // 8 x 2 MB bf16

    prep_w<<<192, 256, 0, stream>>>(dwq, pwq, dwk, pwk, dwv, pwv, wT);
    proj_qkv<<<768, 256, 0, stream>>>(x, wT, bq, bk, bv, qf, kf, vf);
    pass1_rl<<<512, 512, 0, stream>>>(qf, kf, vf, vfs);
    pass2_att<<<1024, 256, 0, stream>>>(qf, kf, vfs, attp);
    final_out<<<2048, 256, 0, stream>>>(attp, gco, dwa, pwa, ba, out);
}